// Round 9
// baseline (433.834 us; speedup 1.0000x reference)
//
#include <hip/hip_runtime.h>

// Jitter: out[b,c,t] = x[b,c,g[t]], g[t] = replace_mask[t] ? neighbor(t) : t
// neighbor(t): t==0 -> 1 ; t==T-1 -> T-2 ; else t + (neighbor_bits[t]>0 ? 1 : -1)
// Memory-bound gather: 250 MB in + 250 MB out => ~80us floor at 6.3 TB/s.

__global__ __launch_bounds__(256) void Jitter_84765474553865_kernel(
    const float* __restrict__ x,
    const int*   __restrict__ replace_mask,
    const int*   __restrict__ neighbor_bits,
    float*       __restrict__ out,
    int T, int T4 /* = T/4 */)
{
    int t4 = blockIdx.x * blockDim.x + threadIdx.x;
    if (t4 >= T4) return;
    const long long row = blockIdx.y;           // one (b,c) row per grid.y
    const int t0 = t4 * 4;

    const float* __restrict__ xrow = x + row * (long long)T;

    float4 v;
    float* vp = &v.x;
#pragma unroll
    for (int j = 0; j < 4; ++j) {
        int t = t0 + j;
        int m = replace_mask[t];                // tiny table, L1-resident
        int b = neighbor_bits[t];
        int off = (b > 0) ? 1 : -1;
        int nb = (t == 0) ? 1 : ((t == T - 1) ? (T - 2) : (t + off));
        int g = (m != 0) ? nb : t;
        vp[j] = xrow[g];                        // 88% identity -> near-coalesced
    }
    *reinterpret_cast<float4*>(out + row * (long long)T + t0) = v;
}

extern "C" void kernel_launch(void* const* d_in, const int* in_sizes, int n_in,
                              void* d_out, int out_size, void* d_ws, size_t ws_size,
                              hipStream_t stream) {
    const float* x             = (const float*)d_in[0];
    const int*   replace_mask  = (const int*)d_in[1];
    const int*   neighbor_bits = (const int*)d_in[2];
    float*       out           = (float*)d_out;

    const int T    = in_sizes[1];          // 4000
    const int rows = in_sizes[0] / T;      // B*C = 16384
    const int T4   = T / 4;                // 1000 (T divisible by 4)

    dim3 block(256, 1, 1);
    dim3 grid((T4 + 255) / 256, rows, 1);  // (4, 16384)
    Jitter_84765474553865_kernel<<<grid, block, 0, stream>>>(
        x, replace_mask, neighbor_bits, out, T, T4);
}

// Round 13
// 416.384 us; speedup vs baseline: 1.0419x; 1.0419x over previous
//
#include <hip/hip_runtime.h>

// Jitter: out[b,c,t] = x[b,c,g[t]], g[t] = replace_mask[t] ? neighbor(t) : t
// neighbor(t): t==0 -> 1 ; t==T-1 -> T-2 ; else t + (neighbor_bits[t]>0 ? 1 : -1)
//
// Structure: one coalesced float4 load per lane (64 lanes = 1KB contiguous),
// then branchless in-register fixup. All gather targets lie in [t0-1, t0+4]:
//   t0-1 = prev lane's v.w (__shfl_up), t0+4 = next lane's v.x (__shfl_down),
//   everything else is within this lane's own float4.
// Wave-edge lanes (0/63) fall back to a predicated scalar load (L1/L2-hit).
// T%4==0 and T-1 ≡ 3 (mod 4), so t==0 only occurs at j=0 and t==T-1 only at j=3.

__global__ __launch_bounds__(256) void Jitter_84765474553865_kernel(
    const float* __restrict__ x,
    const int*   __restrict__ replace_mask,
    const int*   __restrict__ neighbor_bits,
    float*       __restrict__ out,
    int T, int T4 /* = T/4 */)
{
    int t4 = blockIdx.x * blockDim.x + threadIdx.x;
    if (t4 >= T4) return;
    const long long row = blockIdx.y;            // one (b,c) row per grid.y
    const int t0 = t4 * 4;

    const float* __restrict__ xrow = x + row * (long long)T;

    float4 v = *reinterpret_cast<const float4*>(xrow + t0);          // coalesced 16B
    int4   m = *reinterpret_cast<const int4*>(replace_mask + t0);    // L1-resident tables
    int4   b = *reinterpret_cast<const int4*>(neighbor_bits + t0);

    const int lane = threadIdx.x & 63;
    float left  = __shfl_up(v.w, 1);    // element t0-1 (prev lane's v.w)
    float right = __shfl_down(v.x, 1);  // element t0+4 (next lane's v.x)
    if (lane == 0)  left  = xrow[t0 > 0 ? t0 - 1 : 0];       // wave edge; t0==0 case unused
    if (lane == 63) right = xrow[t0 + 4 < T ? t0 + 4 : T-1]; // wave edge; t0+4==T case unused

    // j=0: t==0 -> v.y ; off=+1 -> v.y ; off=-1 -> left
    float o0 = m.x ? ((t0 == 0 || b.x > 0) ? v.y : left)  : v.x;
    // j=1: off=+1 -> v.z ; off=-1 -> v.x
    float o1 = m.y ? ((b.y > 0) ? v.z : v.x)              : v.y;
    // j=2: off=+1 -> v.w ; off=-1 -> v.y
    float o2 = m.z ? ((b.z > 0) ? v.w : v.y)              : v.z;
    // j=3: t==T-1 -> v.z (=T-2) ; off=-1 -> v.z ; off=+1 -> right
    float o3 = m.w ? ((t0 + 4 == T || b.w <= 0) ? v.z : right) : v.w;

    *reinterpret_cast<float4*>(out + row * (long long)T + t0) = float4{o0, o1, o2, o3};
}

extern "C" void kernel_launch(void* const* d_in, const int* in_sizes, int n_in,
                              void* d_out, int out_size, void* d_ws, size_t ws_size,
                              hipStream_t stream) {
    const float* x             = (const float*)d_in[0];
    const int*   replace_mask  = (const int*)d_in[1];
    const int*   neighbor_bits = (const int*)d_in[2];
    float*       out           = (float*)d_out;

    const int T    = in_sizes[1];          // 4000
    const int rows = in_sizes[0] / T;      // B*C = 16384
    const int T4   = T / 4;                // 1000

    dim3 block(256, 1, 1);
    dim3 grid((T4 + 255) / 256, rows, 1);  // (4, 16384)
    Jitter_84765474553865_kernel<<<grid, block, 0, stream>>>(
        x, replace_mask, neighbor_bits, out, T, T4);
}